// Round 10
// baseline (1923.565 us; speedup 1.0000x reference)
//
#include <hip/hip_runtime.h>

#define NQ 273

typedef float f4 __attribute__((ext_vector_type(4)));

// ---------------- compile-time GA tables (Cl(3,0,1) PGA, 16 blades) ----------------
struct GATab {
  int qi[NQ]; int qj[NQ]; int qk[NQ];
  float qs[NQ];
  int qgp[NQ];
  int qpath[NQ];
  int ngp, njp, nq;
};

constexpr int popc4(int m){ int c=0; for(int b=0;b<5;++b) c+=(m>>b)&1; return c; }
constexpr int swap_par(int a,int b){ int s=0; a>>=1; while(a){ s+=popc4(a&b); a>>=1; } return s&1; }

constexpr GATab make_tab(){
  GATab t{};
  int bladeOf[16]={}; int idxOf[16]={};
  { int p=0;
    for(int g=0; g<=4; ++g)
      for(int m=0; m<16; ++m)
        if(popc4(m)==g){ bladeOf[p]=m; idxOf[m]=p; ++p; }
  }
  int grade[16]={};
  for(int j=0;j<16;++j) grade[j]=popc4(bladeOf[j]);
  bool gpp[125]={}; bool jpp[125]={};
  for(int j=0;j<16;++j) for(int k=0;k<16;++k){
    int mj=bladeOf[j], mk=bladeOf[k];
    if(!(mj&mk&1)){ int i=idxOf[mj^mk]; gpp[(grade[i]*5+grade[j])*5+grade[k]]=true; }
    int cj=15^mj, ck=15^mk;
    if(!(cj&ck)){ int r=mj&mk; int i=idxOf[r]; jpp[(grade[i]*5+grade[j])*5+grade[k]]=true; }
  }
  int gpidx[125]={}; int jpidx[125]={};
  { int c=0; for(int u=0;u<125;++u){ gpidx[u] = gpp[u]? c++ : -1; } t.ngp=c; }
  { int c=0; for(int u=0;u<125;++u){ jpidx[u] = jpp[u]? c++ : -1; } t.njp=c; }
  int q=0;
  for(int j=0;j<16;++j) for(int k=0;k<16;++k){
    int mj=bladeOf[j], mk=bladeOf[k];
    if(!(mj&mk&1)){
      int i=idxOf[mj^mk];
      t.qi[q]=i; t.qj[q]=j; t.qk[q]=k;
      t.qs[q] = swap_par(mj,mk) ? -1.0f : 1.0f;
      t.qgp[q]=1;
      t.qpath[q]=gpidx[(grade[i]*5+grade[j])*5+grade[k]];
      ++q;
    }
  }
  for(int j=0;j<16;++j) for(int k=0;k<16;++k){
    int mj=bladeOf[j], mk=bladeOf[k];
    int cj=15^mj, ck=15^mk;
    if(!(cj&ck)){
      int r=mj&mk; int i=idxOf[r];
      int par = swap_par(mj,15^mj) ^ swap_par(mk,15^mk) ^ swap_par(cj,ck) ^ swap_par(r,15^r);
      t.qi[q]=i; t.qj[q]=j; t.qk[q]=k;
      t.qs[q] = par ? -1.0f : 1.0f;
      t.qgp[q]=0;
      t.qpath[q]=jpidx[(grade[i]*5+grade[j])*5+grade[k]];
      ++q;
    }
  }
  t.nq=q;
  return t;
}

constexpr GATab TAB = make_tab();
static_assert(TAB.nq == NQ, "nonzero count mismatch");
static_assert(TAB.ngp > 0 && TAB.njp > 0, "path counts");
constexpr int NGPC = TAB.ngp;
constexpr int NJPC = TAB.njp;
constexpr int GR[16] = {0,1,1,1,1,2,2,2,2,2,2,3,3,3,3,4};

// ---------------- prep kernels ----------------
// repack lin_weight (128,64,5) -> wrp[i][n][12]:
//   s in [0,5):  w1 grade s for output channel n      (o = n)
//   s in [5,10): w2 grade s-5 for output channel n+64 (o = 64+n)
//   s in [10,12): pad -> 48 B record, 3x dwordx4 per (i,n)
__global__ void prep_wrp(const float* __restrict__ linw, float* __restrict__ wrp){
  int t = blockIdx.x*blockDim.x + threadIdx.x;
  if(t < 64*64*12){
    int s = t % 12;
    int n = (t/12) & 63;
    int i = t/(12*64);
    float v = 0.f;
    if(s < 5)       v = linw[(n*64 + i)*5 + s];
    else if(s < 10) v = linw[((64+n)*64 + i)*5 + (s-5)];
    wrp[t] = v;
  }
}

// coef[q][n] = sign_q * (gp? gpw[n][path] : jpw[n][path]);  fully unrolled -> TAB folds
__global__ void prep_coef(const float* __restrict__ gpw, const float* __restrict__ jpw,
                          float* __restrict__ coef){
  int n = threadIdx.x; // blockDim = 64, grid = 1
  #pragma unroll
  for(int q=0;q<NQ;++q){
    float w = TAB.qgp[q] ? gpw[n*NGPC + TAB.qpath[q]] : jpw[n*NJPC + TAB.qpath[q]];
    coef[q*64 + n] = TAB.qs[q]*w;
  }
}

// ---------------- main fused kernel ----------------
// R5 structure with two linked changes:
//  1. x is WAVE-UNIFORM per (i,v): load it through a readfirstlane-uniform
//     pointer (-> s_load / uniform VMEM, hardware broadcast). Removes the
//     1024 v_readlane/element (27% of R5's VALU issue) and frees the 16-reg
//     xr staging block.
//  2. NB=2 per wave using the freed registers: one 192 KB weight pass feeds
//     two elements -> L2 weight stream halves (12.8 -> 6.4 GB), coef LDS
//     reads halve. Live set y64+acc32+w12+addr ~115 < the 128-VGPR cap of
//     512-thread blocks (previous NB=2 attempts carried 32 xr regs; R7/R8
//     proved the cap immovable, so we fit under it instead).
//  - i-loop unroll 1: bounds in-flight regs; 16 waves/CU (2 blk x 8 waves,
//    scratch-free) hides weight-load latency via TLP instead of ILP.
//  - coef (68 KB) in LDS, stride-1 per lane -> 0 bank conflicts (proven R5).
//  - NO sched_barrier (R8), NO 256-thr/256-VGPR tier (R9).
__global__ __launch_bounds__(512)
void main_k(const float* __restrict__ x, const float* __restrict__ coef,
            const float* __restrict__ wrp, float* __restrict__ out, int B){
  __shared__ float cl[NQ*64];   // 68.25 KB -> 2 blocks/CU

  const int tid  = threadIdx.x;
  const int lane = tid & 63;
  const int wv   = tid >> 6;        // 0..7
  const int n    = lane;

  // ---- stage coef once per block: 4368 f4 / 512 thr = 9 chunks (guarded) ----
  {
    const f4* src = (const f4*)coef;
    f4* dst = (f4*)cl;
    #pragma unroll
    for(int k=0;k<9;++k){
      int idx = tid + k*512;
      if(idx < NQ*16) dst[idx] = src[idx];
    }
  }
  __syncthreads();

  for(int base = blockIdx.x*16; base < B; base += gridDim.x*16){
    const int b0r = base + wv*2;            // real (guard) index, even
    int bc = b0r; if(bc > B-2) bc = B-2;    // clamp (B even here; OOB waves compute junk, skip store)
    const int b0 = __builtin_amdgcn_readfirstlane(bc);   // force wave-uniform
    const float* xp0 = x + (long)b0*1024;   // uniform pointers -> scalar/uniform loads
    const float* xp1 = xp0 + 1024;

    // ---- linear phase: y{1,2}[t][v] = sum_i w{1,2}[g(v)] * x[b0+t][i][v] ----
    float y1[2][16], y2[2][16];
    #pragma unroll
    for(int v=0;v<16;++v){ y1[0][v]=0.f; y1[1][v]=0.f; y2[0][v]=0.f; y2[1][v]=0.f; }

    #pragma unroll 1
    for(int i=0;i<64;++i){
      const f4* wp = (const f4*)(wrp + (i*64 + n)*12);
      f4 wa = wp[0], wb = wp[1], wc = wp[2];
      float w1[5] = {wa[0],wa[1],wa[2],wa[3],wb[0]};
      float w2[5] = {wb[1],wb[2],wb[3],wc[0],wc[1]};

      const f4* xq0 = (const f4*)(xp0 + i*16);   // wave-uniform addresses
      const f4* xq1 = (const f4*)(xp1 + i*16);
      f4 A0=xq0[0], A1=xq0[1], A2=xq0[2], A3=xq0[3];
      f4 C0=xq1[0], C1=xq1[1], C2=xq1[2], C3=xq1[3];
      float xv0[16]={A0[0],A0[1],A0[2],A0[3], A1[0],A1[1],A1[2],A1[3],
                     A2[0],A2[1],A2[2],A2[3], A3[0],A3[1],A3[2],A3[3]};
      float xv1[16]={C0[0],C0[1],C0[2],C0[3], C1[0],C1[1],C1[2],C1[3],
                     C2[0],C2[1],C2[2],C2[3], C3[0],C3[1],C3[2],C3[3]};

      #pragma unroll
      for(int v=0;v<16;++v){
        float g1 = w1[GR[v]], g2 = w2[GR[v]];
        y1[0][v] = fmaf(g1, xv0[v], y1[0][v]);
        y2[0][v] = fmaf(g2, xv0[v], y2[0][v]);
        y1[1][v] = fmaf(g1, xv1[v], y1[1][v]);
        y2[1][v] = fmaf(g2, xv1[v], y2[1][v]);
      }
    }

    // ---- bilinear phase: acc[i] = y2[i] + sum_q coef[n,q]*y1[j_q]*y2[k_q] ----
    float acc[2][16];
    #pragma unroll
    for(int v=0;v<16;++v){ acc[0][v]=y2[0][v]; acc[1][v]=y2[1][v]; }

    #pragma unroll
    for(int q=0;q<NQ;++q){
      float c = cl[q*64 + n];        // one LDS read feeds both elements
      acc[0][TAB.qi[q]] = fmaf(c, y1[0][TAB.qj[q]]*y2[0][TAB.qk[q]], acc[0][TAB.qi[q]]);
      acc[1][TAB.qi[q]] = fmaf(c, y1[1][TAB.qj[q]]*y2[1][TAB.qk[q]], acc[1][TAB.qi[q]]);
    }

    // ---- store (streamed once -> nontemporal); guard with real index ----
    #pragma unroll
    for(int t=0;t<2;++t){
      if(b0r + t < B){
        f4* op = (f4*)(out + ((long)(b0 + t)*64 + n)*16);
        #pragma unroll
        for(int r=0;r<4;++r){
          f4 o; o[0]=acc[t][4*r]; o[1]=acc[t][4*r+1]; o[2]=acc[t][4*r+2]; o[3]=acc[t][4*r+3];
          __builtin_nontemporal_store(o, op+r);
        }
      }
    }
  }
}

extern "C" void kernel_launch(void* const* d_in, const int* in_sizes, int n_in,
                              void* d_out, int out_size, void* d_ws, size_t ws_size,
                              hipStream_t stream){
  const float* x    = (const float*)d_in[0];
  const float* gpw  = (const float*)d_in[1];
  const float* jpw  = (const float*)d_in[2];
  const float* linw = (const float*)d_in[3];
  float* outp = (float*)d_out;

  float* wrp  = (float*)d_ws;          // 64*64*12 floats = 192 KB
  float* coef = wrp + 64*64*12;        // NQ*64 floats ≈ 68 KB

  int B = in_sizes[0] / (64*16);

  prep_wrp <<<192, 256, 0, stream>>>(linw, wrp);
  prep_coef<<<1,   64,  0, stream>>>(gpw, jpw, coef);
  main_k   <<<512, 512, 0, stream>>>(x, coef, wrp, outp, B);
}

// Round 11
// 1018.827 us; speedup vs baseline: 1.8880x; 1.8880x over previous
//
#include <hip/hip_runtime.h>

#define NQ 273

typedef float f4 __attribute__((ext_vector_type(4)));

// ---------------- compile-time GA tables (Cl(3,0,1) PGA, 16 blades) ----------------
struct GATab {
  int qi[NQ]; int qj[NQ]; int qk[NQ];
  float qs[NQ];
  int qgp[NQ];
  int qpath[NQ];
  int ngp, njp, nq;
};

constexpr int popc4(int m){ int c=0; for(int b=0;b<5;++b) c+=(m>>b)&1; return c; }
constexpr int swap_par(int a,int b){ int s=0; a>>=1; while(a){ s+=popc4(a&b); a>>=1; } return s&1; }

constexpr GATab make_tab(){
  GATab t{};
  int bladeOf[16]={}; int idxOf[16]={};
  { int p=0;
    for(int g=0; g<=4; ++g)
      for(int m=0; m<16; ++m)
        if(popc4(m)==g){ bladeOf[p]=m; idxOf[m]=p; ++p; }
  }
  int grade[16]={};
  for(int j=0;j<16;++j) grade[j]=popc4(bladeOf[j]);
  bool gpp[125]={}; bool jpp[125]={};
  for(int j=0;j<16;++j) for(int k=0;k<16;++k){
    int mj=bladeOf[j], mk=bladeOf[k];
    if(!(mj&mk&1)){ int i=idxOf[mj^mk]; gpp[(grade[i]*5+grade[j])*5+grade[k]]=true; }
    int cj=15^mj, ck=15^mk;
    if(!(cj&ck)){ int r=mj&mk; int i=idxOf[r]; jpp[(grade[i]*5+grade[j])*5+grade[k]]=true; }
  }
  int gpidx[125]={}; int jpidx[125]={};
  { int c=0; for(int u=0;u<125;++u){ gpidx[u] = gpp[u]? c++ : -1; } t.ngp=c; }
  { int c=0; for(int u=0;u<125;++u){ jpidx[u] = jpp[u]? c++ : -1; } t.njp=c; }
  int q=0;
  for(int j=0;j<16;++j) for(int k=0;k<16;++k){
    int mj=bladeOf[j], mk=bladeOf[k];
    if(!(mj&mk&1)){
      int i=idxOf[mj^mk];
      t.qi[q]=i; t.qj[q]=j; t.qk[q]=k;
      t.qs[q] = swap_par(mj,mk) ? -1.0f : 1.0f;
      t.qgp[q]=1;
      t.qpath[q]=gpidx[(grade[i]*5+grade[j])*5+grade[k]];
      ++q;
    }
  }
  for(int j=0;j<16;++j) for(int k=0;k<16;++k){
    int mj=bladeOf[j], mk=bladeOf[k];
    int cj=15^mj, ck=15^mk;
    if(!(cj&ck)){
      int r=mj&mk; int i=idxOf[r];
      int par = swap_par(mj,15^mj) ^ swap_par(mk,15^mk) ^ swap_par(cj,ck) ^ swap_par(r,15^r);
      t.qi[q]=i; t.qj[q]=j; t.qk[q]=k;
      t.qs[q] = par ? -1.0f : 1.0f;
      t.qgp[q]=0;
      t.qpath[q]=jpidx[(grade[i]*5+grade[j])*5+grade[k]];
      ++q;
    }
  }
  t.nq=q;
  return t;
}

constexpr GATab TAB = make_tab();
static_assert(TAB.nq == NQ, "nonzero count mismatch");
static_assert(TAB.ngp > 0 && TAB.njp > 0, "path counts");
constexpr int NGPC = TAB.ngp;
constexpr int NJPC = TAB.njp;
constexpr int GR[16] = {0,1,1,1,1,2,2,2,2,2,2,3,3,3,3,4};

__device__ __forceinline__ float rdlane(float v, int i){
  return __uint_as_float((unsigned)__builtin_amdgcn_readlane((int)__float_as_uint(v), i));
}

// ---------------- prep kernels ----------------
// repack lin_weight (128,64,5) -> wrp[i][n][12]:
//   s in [0,5):  w1 grade s for output channel n      (o = n)
//   s in [5,10): w2 grade s-5 for output channel n+64 (o = 64+n)
//   s in [10,12): pad -> 48 B record, 3x dwordx4 per (i,n)
__global__ void prep_wrp(const float* __restrict__ linw, float* __restrict__ wrp){
  int t = blockIdx.x*blockDim.x + threadIdx.x;
  if(t < 64*64*12){
    int s = t % 12;
    int n = (t/12) & 63;
    int i = t/(12*64);
    float v = 0.f;
    if(s < 5)       v = linw[(n*64 + i)*5 + s];
    else if(s < 10) v = linw[((64+n)*64 + i)*5 + (s-5)];
    wrp[t] = v;
  }
}

// coef[q][n] = sign_q * (gp? gpw[n][path] : jpw[n][path]);  fully unrolled -> TAB folds
__global__ void prep_coef(const float* __restrict__ gpw, const float* __restrict__ jpw,
                          float* __restrict__ coef){
  int n = threadIdx.x; // blockDim = 64, grid = 1
  #pragma unroll
  for(int q=0;q<NQ;++q){
    float w = TAB.qgp[q] ? gpw[n*NGPC + TAB.qpath[q]] : jpw[n*NJPC + TAB.qpath[q]];
    coef[q*64 + n] = TAB.qs[q]*w;
  }
}

// ---------------- main fused kernel ----------------
// R5's exact data path at 256 threads/block (the one untested cell):
//  - 256-thr blocks -> 256-VGPR tier (proven R3/R6/R9). NB=1 live set ~100
//    floats (xr16 + y32 + acc16 + w12 + addr) even x1.5 pipelining < 256
//    -> genuinely spill-free. (512-thr = 128 cap -> R5's 18-float spill;
//    NB=2 = 160+ live -> spills even at 256, R9.)
//  - coef (68 KB) in LDS, stride-1 per lane -> 0 conflicts; removes the
//    273-global-load hoist (R5's fix for R3's spill).
//  - x per-lane in 16 VGPRs; lane i broadcast via v_readlane.
//  - weights stream from L2 (192 KB, resident; FETCH ~135 MB proven).
//  - NO sched_barrier (R8), NO f2 packing (R6), NO uniform-x (R10).
// Geometry: 68 KB -> 2 blocks/CU; 256 VGPR -> 2 waves/SIMD = 8 waves/CU,
// all realizable (no scratch throttle, unlike R5's 6.4).
__global__ __launch_bounds__(256)
void main_k(const float* __restrict__ x, const float* __restrict__ coef,
            const float* __restrict__ wrp, float* __restrict__ out, int B){
  __shared__ float cl[NQ*64];   // 68.25 KB

  const int tid  = threadIdx.x;
  const int lane = tid & 63;
  const int wv   = tid >> 6;        // 0..3
  const int n    = lane;

  // ---- stage coef once per block: 4368 f4 / 256 thr = 18 chunks (guarded) ----
  {
    const f4* src = (const f4*)coef;
    f4* dst = (f4*)cl;
    #pragma unroll
    for(int k=0;k<18;++k){
      int idx = tid + k*256;
      if(idx < NQ*16) dst[idx] = src[idx];
    }
  }
  __syncthreads();

  for(int base = blockIdx.x*4; base < B; base += gridDim.x*4){
    const int bb = base + wv;

    // ---- load this wave's batch element into registers (lane = channel) ----
    f4 xr[4];
    if(bb < B){
      const f4* src = (const f4*)(x + ((long)bb*64 + lane)*16);
      #pragma unroll
      for(int r=0;r<4;++r) xr[r] = __builtin_nontemporal_load(src+r);
    }

    // ---- linear phase: y1[v] = sum_i w1[g(v)]*x[i][v], y2 likewise ----
    float y1[16], y2[16];
    #pragma unroll
    for(int v=0;v<16;++v){ y1[v]=0.f; y2[v]=0.f; }

    #pragma unroll 2
    for(int i=0;i<64;++i){
      const f4* wp = (const f4*)(wrp + (i*64 + n)*12);
      f4 wa = wp[0], wb = wp[1], wc = wp[2];
      float w1[5] = {wa[0],wa[1],wa[2],wa[3],wb[0]};
      float w2[5] = {wb[1],wb[2],wb[3],wc[0],wc[1]};
      #pragma unroll
      for(int v=0;v<16;++v){
        float xv = rdlane(xr[v>>2][v&3], i);   // x[bb][i][v], wave-uniform (SGPR)
        y1[v] = fmaf(w1[GR[v]], xv, y1[v]);
        y2[v] = fmaf(w2[GR[v]], xv, y2[v]);
      }
    }

    // ---- bilinear phase: acc[i] = y2[i] + sum_q coef[n,q]*y1[j_q]*y2[k_q] ----
    float acc[16];
    #pragma unroll
    for(int v=0;v<16;++v) acc[v]=y2[v];

    #pragma unroll
    for(int q=0;q<NQ;++q){
      float c = cl[q*64 + n];
      acc[TAB.qi[q]] = fmaf(c, y1[TAB.qj[q]]*y2[TAB.qk[q]], acc[TAB.qi[q]]);
    }

    // ---- store (streamed once -> nontemporal) ----
    if(bb < B){
      f4* op = (f4*)(out + ((long)bb*64 + n)*16);
      #pragma unroll
      for(int r=0;r<4;++r){
        f4 o; o[0]=acc[4*r]; o[1]=acc[4*r+1]; o[2]=acc[4*r+2]; o[3]=acc[4*r+3];
        __builtin_nontemporal_store(o, op+r);
      }
    }
  }
}

extern "C" void kernel_launch(void* const* d_in, const int* in_sizes, int n_in,
                              void* d_out, int out_size, void* d_ws, size_t ws_size,
                              hipStream_t stream){
  const float* x    = (const float*)d_in[0];
  const float* gpw  = (const float*)d_in[1];
  const float* jpw  = (const float*)d_in[2];
  const float* linw = (const float*)d_in[3];
  float* outp = (float*)d_out;

  float* wrp  = (float*)d_ws;          // 64*64*12 floats = 192 KB
  float* coef = wrp + 64*64*12;        // NQ*64 floats ≈ 68 KB

  int B = in_sizes[0] / (64*16);

  prep_wrp <<<192, 256, 0, stream>>>(linw, wrp);
  prep_coef<<<1,   64,  0, stream>>>(gpw, jpw, coef);
  main_k   <<<1024, 256, 0, stream>>>(x, coef, wrp, outp, B);
}

// Round 12
// 727.161 us; speedup vs baseline: 2.6453x; 1.4011x over previous
//
#include <hip/hip_runtime.h>

#define NQ 273

typedef float f4 __attribute__((ext_vector_type(4)));

// ---------------- compile-time GA tables (Cl(3,0,1) PGA, 16 blades) ----------------
struct GATab {
  int qi[NQ]; int qj[NQ]; int qk[NQ];
  float qs[NQ];
  int qgp[NQ];
  int qpath[NQ];
  int ngp, njp, nq;
};

constexpr int popc4(int m){ int c=0; for(int b=0;b<5;++b) c+=(m>>b)&1; return c; }
constexpr int swap_par(int a,int b){ int s=0; a>>=1; while(a){ s+=popc4(a&b); a>>=1; } return s&1; }

constexpr GATab make_tab(){
  GATab t{};
  int bladeOf[16]={}; int idxOf[16]={};
  { int p=0;
    for(int g=0; g<=4; ++g)
      for(int m=0; m<16; ++m)
        if(popc4(m)==g){ bladeOf[p]=m; idxOf[m]=p; ++p; }
  }
  int grade[16]={};
  for(int j=0;j<16;++j) grade[j]=popc4(bladeOf[j]);
  bool gpp[125]={}; bool jpp[125]={};
  for(int j=0;j<16;++j) for(int k=0;k<16;++k){
    int mj=bladeOf[j], mk=bladeOf[k];
    if(!(mj&mk&1)){ int i=idxOf[mj^mk]; gpp[(grade[i]*5+grade[j])*5+grade[k]]=true; }
    int cj=15^mj, ck=15^mk;
    if(!(cj&ck)){ int r=mj&mk; int i=idxOf[r]; jpp[(grade[i]*5+grade[j])*5+grade[k]]=true; }
  }
  int gpidx[125]={}; int jpidx[125]={};
  { int c=0; for(int u=0;u<125;++u){ gpidx[u] = gpp[u]? c++ : -1; } t.ngp=c; }
  { int c=0; for(int u=0;u<125;++u){ jpidx[u] = jpp[u]? c++ : -1; } t.njp=c; }
  int q=0;
  for(int j=0;j<16;++j) for(int k=0;k<16;++k){
    int mj=bladeOf[j], mk=bladeOf[k];
    if(!(mj&mk&1)){
      int i=idxOf[mj^mk];
      t.qi[q]=i; t.qj[q]=j; t.qk[q]=k;
      t.qs[q] = swap_par(mj,mk) ? -1.0f : 1.0f;
      t.qgp[q]=1;
      t.qpath[q]=gpidx[(grade[i]*5+grade[j])*5+grade[k]];
      ++q;
    }
  }
  for(int j=0;j<16;++j) for(int k=0;k<16;++k){
    int mj=bladeOf[j], mk=bladeOf[k];
    int cj=15^mj, ck=15^mk;
    if(!(cj&ck)){
      int r=mj&mk; int i=idxOf[r];
      int par = swap_par(mj,15^mj) ^ swap_par(mk,15^mk) ^ swap_par(cj,ck) ^ swap_par(r,15^r);
      t.qi[q]=i; t.qj[q]=j; t.qk[q]=k;
      t.qs[q] = par ? -1.0f : 1.0f;
      t.qgp[q]=0;
      t.qpath[q]=jpidx[(grade[i]*5+grade[j])*5+grade[k]];
      ++q;
    }
  }
  t.nq=q;
  return t;
}

constexpr GATab TAB = make_tab();
static_assert(TAB.nq == NQ, "nonzero count mismatch");
static_assert(TAB.ngp > 0 && TAB.njp > 0, "path counts");
constexpr int NGPC = TAB.ngp;
constexpr int NJPC = TAB.njp;
constexpr int GR[16] = {0,1,1,1,1,2,2,2,2,2,2,3,3,3,3,4};

// compact coef tables: odd-padded rows -> per-lane stride odd -> 2-way bank
// aliasing only (free, m136). Signs fold into compile-time +-prod in the fma.
constexpr int PADG = (NGPC & 1) ? NGPC : NGPC + 1;
constexpr int PADJ = (NJPC & 1) ? NJPC : NJPC + 1;
constexpr int CGF  = 64 * PADG;          // floats
constexpr int CJF  = 64 * PADJ;          // floats
constexpr int XLF  = 8 * 64 * 16;        // x staging: 8 waves x 64 i x 16 v = 32 KB
static_assert((CGF + CJF + XLF) * 4 <= 80 * 1024, "2 blocks/CU requires <=80KB");

// ---------------- prep kernels ----------------
// repack lin_weight (128,64,5) -> wrp[i][n][12]:
//   s in [0,5):  w1 grade s for output channel n      (o = n)
//   s in [5,10): w2 grade s-5 for output channel n+64 (o = 64+n)
//   s in [10,12): pad -> 48 B record, 3x dwordx4 per (i,n)
__global__ void prep_wrp(const float* __restrict__ linw, float* __restrict__ wrp){
  int t = blockIdx.x*blockDim.x + threadIdx.x;
  if(t < 64*64*12){
    int s = t % 12;
    int n = (t/12) & 63;
    int i = t/(12*64);
    float v = 0.f;
    if(s < 5)       v = linw[(n*64 + i)*5 + s];
    else if(s < 10) v = linw[((64+n)*64 + i)*5 + (s-5)];
    wrp[t] = v;
  }
}

// pack gpw/jpw raw into odd-padded rows: cgj[n*PADG+p] , cgj[CGF + n*PADJ+p]
__global__ void prep_cpk(const float* __restrict__ gpw, const float* __restrict__ jpw,
                         float* __restrict__ cgj){
  int n = threadIdx.x; // blockDim = 64, grid = 1
  for(int p=0;p<NGPC;++p) cgj[n*PADG + p] = gpw[n*NGPC + p];
  for(int p=0;p<NJPC;++p) cgj[CGF + n*PADJ + p] = jpw[n*NJPC + p];
}

// ---------------- main fused kernel ----------------
// Spill-free geometry + rdlane elimination:
//  - x staged in LDS per wave (4 KB), read back as WAVE-UNIFORM broadcast
//    ds_read_b128 (conflict-free, LDS pipe not VALU). Removes 1024
//    v_readlane/element (~28% of R5's VALU issue) and the 16 xr VGPRs.
//    XOR swizzle ((row&7)<<2 dwords) keeps the b128 stage-writes at the
//    bank-BW floor; reads use the same formula (uniform -> broadcast).
//  - coef stored RAW (gpw/jpw, ~26 KB padded) instead of expanded 68 KB;
//    sign folds into compile-time +-prod. Per-lane row stride odd -> 2-way
//    aliasing = free.
//  - LDS/block ~58 KB -> 2 blocks/CU x 8 waves = 16 waves/CU nominal; live
//    set ~80 floats << 128 cap -> NO spill -> nominal occupancy realized.
//  - weights stream from L2 (unchanged, ~12.6 GB aggregate = the next floor).
__global__ __launch_bounds__(512)
void main_k(const float* __restrict__ x, const float* __restrict__ cgj,
            const float* __restrict__ wrp, float* __restrict__ out, int B){
  __shared__ float lds[CGF + CJF + XLF];
  float* clg = lds;
  float* clj = lds + CGF;
  float* xl  = lds + CGF + CJF;

  const int tid  = threadIdx.x;
  const int lane = tid & 63;
  const int wv   = tid >> 6;        // 0..7
  const int n    = lane;

  // ---- stage compact coef tables once per block ----
  for(int idx = tid; idx < CGF + CJF; idx += 512) lds[idx] = cgj[idx];
  __syncthreads();

  const int cgbase = n*PADG;
  const int cjbase = n*PADJ;
  float* xw = xl + wv*1024;        // this wave's 64x16 staging region

  for(int base = blockIdx.x*8; base < B; base += gridDim.x*8){
    const int bb = base + wv;

    // ---- stage x: lane writes its channel row (swizzled b128, bank-floor) ----
    if(bb < B){
      const f4* src = (const f4*)(x + ((long)bb*64 + lane)*16);
      #pragma unroll
      for(int r=0;r<4;++r){
        f4 a = __builtin_nontemporal_load(src+r);
        int daddr = (lane*16 + r*4) ^ ((lane&7)<<2);
        *(f4*)(xw + daddr) = a;
      }
    }
    // (per-wave region: in-wave lgkmcnt ordering suffices, no __syncthreads)

    // ---- linear phase: y1[v] = sum_i w1[g(v)]*x[i][v], y2 likewise ----
    float y1[16], y2[16];
    #pragma unroll
    for(int v=0;v<16;++v){ y1[v]=0.f; y2[v]=0.f; }

    #pragma unroll 2
    for(int i=0;i<64;++i){
      const f4* wp = (const f4*)(wrp + (i*64 + n)*12);
      f4 wa = wp[0], wb = wp[1], wc = wp[2];
      float w1[5] = {wa[0],wa[1],wa[2],wa[3],wb[0]};
      float w2[5] = {wb[1],wb[2],wb[3],wc[0],wc[1]};

      // broadcast reads of x[bb][i][0..15]: uniform address, conflict-free
      float xv[16];
      #pragma unroll
      for(int g=0;g<4;++g){
        int raddr = (i*16 + g*4) ^ ((i&7)<<2);
        f4 a = *(const f4*)(xw + raddr);
        xv[g*4+0]=a[0]; xv[g*4+1]=a[1]; xv[g*4+2]=a[2]; xv[g*4+3]=a[3];
      }

      #pragma unroll
      for(int v=0;v<16;++v){
        y1[v] = fmaf(w1[GR[v]], xv[v], y1[v]);
        y2[v] = fmaf(w2[GR[v]], xv[v], y2[v]);
      }
    }

    // ---- bilinear phase: acc[i] = y2[i] + sum_q s_q*w_q[n]*y1[j_q]*y2[k_q] ----
    float acc[16];
    #pragma unroll
    for(int v=0;v<16;++v) acc[v]=y2[v];

    #pragma unroll
    for(int q=0;q<NQ;++q){
      float c = TAB.qgp[q] ? clg[cgbase + TAB.qpath[q]] : clj[cjbase + TAB.qpath[q]];
      float prod = y1[TAB.qj[q]] * y2[TAB.qk[q]];
      acc[TAB.qi[q]] = fmaf(c, (TAB.qs[q] < 0.f) ? -prod : prod, acc[TAB.qi[q]]);
    }

    // ---- store (streamed once -> nontemporal) ----
    if(bb < B){
      f4* op = (f4*)(out + ((long)bb*64 + n)*16);
      #pragma unroll
      for(int r=0;r<4;++r){
        f4 o; o[0]=acc[4*r]; o[1]=acc[4*r+1]; o[2]=acc[4*r+2]; o[3]=acc[4*r+3];
        __builtin_nontemporal_store(o, op+r);
      }
    }
  }
}

extern "C" void kernel_launch(void* const* d_in, const int* in_sizes, int n_in,
                              void* d_out, int out_size, void* d_ws, size_t ws_size,
                              hipStream_t stream){
  const float* x    = (const float*)d_in[0];
  const float* gpw  = (const float*)d_in[1];
  const float* jpw  = (const float*)d_in[2];
  const float* linw = (const float*)d_in[3];
  float* outp = (float*)d_out;

  float* wrp = (float*)d_ws;           // 64*64*12 floats = 192 KB
  float* cgj = wrp + 64*64*12;         // CGF+CJF floats (~26 KB)

  int B = in_sizes[0] / (64*16);

  prep_wrp <<<192, 256, 0, stream>>>(linw, wrp);
  prep_cpk <<<1,   64,  0, stream>>>(gpw, jpw, cgj);
  main_k   <<<1024, 512, 0, stream>>>(x, cgj, wrp, outp, B);
}